// Round 16
// baseline (680.957 us; speedup 1.0000x reference)
//
#include <hip/hip_runtime.h>
#include <hip/hip_cooperative_groups.h>
#include <stdint.h>

namespace cg = cooperative_groups;

#define V_ 50257
#define D_ 1024
#define F_ 2048
#define B_ 64
#define E_ 512
#define ROWS_ (B_*E_)

typedef __attribute__((ext_vector_type(8))) short bf16x8;
typedef __attribute__((ext_vector_type(4))) float f32x4;
typedef __attribute__((ext_vector_type(4), aligned(4))) float f32x4a;  // 4B-aligned global loads

__device__ __forceinline__ unsigned rne1(float a) {
  unsigned u = __float_as_uint(a);
  return (u + 0x7FFFu + ((u >> 16) & 1u)) >> 16;
}

// packed bf16 convert: r = bf16(a) | bf16(b)<<16, 1 VALU op per pair.
// hi rounding mode is irrelevant for the split (lo = rne(s - ACTUAL hif) self-corrects).
__device__ __forceinline__ unsigned cvtpk(float a, float b) {
  unsigned r;
  asm("v_cvt_pk_bf16_f32 %0, %1, %2" : "=v"(r) : "v"(a), "v"(b));
  return r;
}

__device__ __forceinline__ float waveMax(float v) {
#pragma unroll
  for (int o = 32; o > 0; o >>= 1) v = fmaxf(v, __shfl_xor(v, o, 64));
  return v;
}
__device__ __forceinline__ float waveSum(float v) {
#pragma unroll
  for (int o = 32; o > 0; o >>= 1) v += __shfl_xor(v, o, 64);
  return v;
}

// ---------------- device bodies ----------------

__device__ __forceinline__ void ent_partial_body(int bid, const float* __restrict__ eh,
                                                 const void* __restrict__ mask,
                                                 float* __restrict__ part) {
  __shared__ int s_mode;
  const int tid = threadIdx.x;
  const uint32_t* mu = (const uint32_t*)mask;
  int f = 0;
  for (int i = tid; i < (ROWS_ / 4); i += 256) {
    uint32_t u = mu[i];
    if (u == 0x3F800000u) f |= 2;
    else if (u & 0xFFFFFF00u) f |= 1;
  }
  if (tid == 0) s_mode = 0;
  __syncthreads();
  if (f) atomicOr(&s_mode, f);
  __syncthreads();
  const int sm = s_mode;
  const int mode = (sm & 1) ? 1 : ((sm & 2) ? 2 : 0);

  float4 acc = make_float4(0.f, 0.f, 0.f, 0.f);
  const float4* eh4 = (const float4*)eh;
  for (int row = bid; row < ROWS_; row += 512) {
    bool on;
    if (mode == 1)      on = ((const unsigned char*)mask)[row] != 0;
    else if (mode == 2) on = ((const float*)mask)[row] != 0.f;
    else                on = ((const int*)mask)[row] != 0;
    if (on) {
      float4 v = eh4[(size_t)row * (D_ / 4) + tid];
      acc.x += v.x; acc.y += v.y; acc.z += v.z; acc.w += v.w;
    }
  }
  ((float4*)part)[(size_t)bid * (D_ / 4) + tid] = acc;
}

__device__ __forceinline__ void ent_reduce_body(int bid, const float* __restrict__ part,
                                                float* __restrict__ entsum) {
  int d = bid * 256 + threadIdx.x;
  float s0 = 0.f, s1 = 0.f, s2 = 0.f, s3 = 0.f;
#pragma unroll 8
  for (int i = 0; i < 512; i += 4) {
    s0 += part[(size_t)(i    ) * D_ + d];
    s1 += part[(size_t)(i + 1) * D_ + d];
    s2 += part[(size_t)(i + 2) * D_ + d];
    s3 += part[(size_t)(i + 3) * D_ + d];
  }
  entsum[d] = (s0 + s1) + (s2 + s3);
}

__device__ __forceinline__ void gemm64_body(int bx, int by, const float* __restrict__ X,
                                            const int* __restrict__ gatherIdx,
                                            const float* __restrict__ emb,
                                            const float* __restrict__ W,
                                            int K, int N, int KB, float* __restrict__ part) {
  const int l  = threadIdx.x & 63;
  const int rg = __builtin_amdgcn_readfirstlane((int)(threadIdx.x >> 6));
  const int c  = bx * 64 + l;
  const int k0 = by * KB;
  const int m0 = rg * 16;

  const float* Xp = gatherIdx ? emb : X;
  int rb[16];
#pragma unroll
  for (int r = 0; r < 16; ++r) {
    int m = m0 + r;
    rb[r] = gatherIdx ? gatherIdx[m] * K : m * K;
  }

  float acc[16];
#pragma unroll
  for (int r = 0; r < 16; ++r) acc[r] = 0.f;

  for (int k = k0; k < k0 + KB; k += 8) {
    float wv[8];
#pragma unroll
    for (int j = 0; j < 8; ++j) wv[j] = W[(size_t)(k + j) * N + c];
#pragma unroll
    for (int r = 0; r < 16; ++r) {
      float4 x0 = *(const float4*)&Xp[rb[r] + k];
      float4 x1 = *(const float4*)&Xp[rb[r] + k + 4];
      acc[r] = fmaf(x0.x, wv[0], acc[r]);
      acc[r] = fmaf(x0.y, wv[1], acc[r]);
      acc[r] = fmaf(x0.z, wv[2], acc[r]);
      acc[r] = fmaf(x0.w, wv[3], acc[r]);
      acc[r] = fmaf(x1.x, wv[4], acc[r]);
      acc[r] = fmaf(x1.y, wv[5], acc[r]);
      acc[r] = fmaf(x1.z, wv[6], acc[r]);
      acc[r] = fmaf(x1.w, wv[7], acc[r]);
    }
  }
  size_t base = (size_t)by * ((size_t)64 * N);
#pragma unroll
  for (int r = 0; r < 16; ++r) part[base + (size_t)(m0 + r) * N + c] = acc[r];
}

// reduce split-K partials + epilogue, compile-time NSPLIT.
// mode 1: relu(x+vecB[c]); 2: x+vecB[c]; 3: x*vecB[c];
// mode 4: idx is zpack DEST index; gathers src, writes bf16 hi/lo in MFMA-fragment order.
template<int NSPLIT>
__device__ __forceinline__ void reduce_body_t(int bid, const float* __restrict__ part,
                                              int MN, int N,
                                              const float* __restrict__ vecB,
                                              const float* __restrict__ addend,
                                              int mode, float* __restrict__ dst,
                                              unsigned short* __restrict__ ph,
                                              unsigned short* __restrict__ pl) {
  int idx = bid * 256 + threadIdx.x;
  if (idx >= MN) return;

  if (mode == 4) {
    const int d   = idx;
    const int j   = d & 7;
    const int l   = (d >> 3) & 63;
    const int m   = (d >> 9) & 3;
    const int tg  = d >> 11;
    const int col = l & 15;
    const int g   = l >> 4;
    const int row = m * 16 + col;
    const int kk  = tg * 32 + g * 8 + j;
    const int src = row * 1024 + kk;
    float s = 0.f;
#pragma unroll
    for (int i = 0; i < NSPLIT; ++i) s += part[(size_t)i * MN + src];
    s += addend[src];
    unsigned hi = rne1(s);
    float hif = __uint_as_float(hi << 16);
    ph[d] = (unsigned short)hi;
    pl[d] = (unsigned short)rne1(s - hif);
    return;
  }

  float s = 0.f;
#pragma unroll
  for (int i = 0; i < NSPLIT; ++i) s += part[(size_t)i * MN + idx];
  int c = idx & (N - 1);
  if (mode == 1)      { s += vecB[c]; s = s > 0.f ? s : 0.f; dst[idx] = s; }
  else if (mode == 2) { s += vecB[c]; dst[idx] = s; }
  else                { s *= vecB[c]; dst[idx] = s; }
}

// ---------------- cooperative fused chain (P1..P8 in one launch) ----------------
__global__ void k_chain(const float* __restrict__ eh, const void* __restrict__ mask,
                        float* __restrict__ entpart, const int* __restrict__ ques,
                        const float* __restrict__ emb, const float* __restrict__ W1,
                        float* __restrict__ gpart, float* __restrict__ entsum,
                        const float* __restrict__ b1, float* __restrict__ hbuf,
                        const float* __restrict__ W2, const float* __restrict__ b2,
                        float* __restrict__ qbuf, const float* __restrict__ A,
                        float* __restrict__ ubuf, const float* __restrict__ H,
                        unsigned short* __restrict__ zpkh, unsigned short* __restrict__ zpkl) {
  cg::grid_group grid = cg::this_grid();
  const int b = blockIdx.x;  // 0..511

  // phase 1: ent partials (512 units) + h-gemm partials (512 units)
  ent_partial_body(b, eh, mask, entpart);
  gemm64_body(b & 31, b >> 5, nullptr, ques, emb, W1, 1024, 2048, 64, gpart);
  grid.sync();
  // phase 2: h = relu(.+b1) (512) + ent_reduce (4)
  reduce_body_t<16>(b, gpart, 64 * 2048, 2048, b1, nullptr, 1, hbuf, nullptr, nullptr);
  if (b < 4) ent_reduce_body(b, entpart, entsum);
  grid.sync();
  // phase 3: q-gemm partials (512 units, 16x32)
  gemm64_body(b & 15, b >> 4, hbuf, nullptr, nullptr, W2, 2048, 1024, 64, gpart);
  grid.sync();
  // phase 4: q = .+b2 (256)
  if (b < 256) reduce_body_t<32>(b, gpart, 64 * 1024, 1024, b2, nullptr, 2, qbuf, nullptr, nullptr);
  grid.sync();
  // phase 5: u-gemm partials (256, 16x16)
  if (b < 256) gemm64_body(b & 15, b >> 4, qbuf, nullptr, nullptr, A, 1024, 1024, 64, gpart);
  grid.sync();
  // phase 6: u = . * entsum (256)
  if (b < 256) reduce_body_t<16>(b, gpart, 64 * 1024, 1024, entsum, nullptr, 3, ubuf, nullptr, nullptr);
  grid.sync();
  // phase 7: z-gemm partials (256)
  if (b < 256) gemm64_body(b & 15, b >> 4, ubuf, nullptr, nullptr, H, 1024, 1024, 64, gpart);
  grid.sync();
  // phase 8: zpack (256)
  if (b < 256) reduce_body_t<16>(b, gpart, 64 * 1024, 1024, nullptr, qbuf, 4, nullptr, zpkh, zpkl);
}

// ---------------- fallback separate kernels (used if cooperative launch fails) -----------
__global__ void k_p1(const float* __restrict__ eh, const void* __restrict__ mask,
                     float* __restrict__ entpart, const int* __restrict__ ques,
                     const float* __restrict__ emb, const float* __restrict__ W1,
                     float* __restrict__ gpart) {
  int bid = blockIdx.x;
  if (bid < 512) ent_partial_body(bid, eh, mask, entpart);
  else {
    int b2 = bid - 512;
    gemm64_body(b2 & 31, b2 >> 5, nullptr, ques, emb, W1, 1024, 2048, 64, gpart);
  }
}

__global__ void k_p2(const float* __restrict__ entpart, float* __restrict__ entsum,
                     const float* __restrict__ gpart, const float* __restrict__ b1,
                     float* __restrict__ hbuf) {
  int bid = blockIdx.x;
  if (bid < 4) ent_reduce_body(bid, entpart, entsum);
  else reduce_body_t<16>(bid - 4, gpart, 64 * 2048, 2048, b1, nullptr, 1, hbuf, nullptr, nullptr);
}

__global__ void k_gemm64(const float* __restrict__ X, const float* __restrict__ W,
                         int K, int N, int KB, float* __restrict__ part) {
  gemm64_body(blockIdx.x, blockIdx.y, X, nullptr, nullptr, W, K, N, KB, part);
}

template<int NSPLIT>
__global__ void k_reduce_t(const float* __restrict__ part, int MN, int N,
                           const float* __restrict__ vecB, const float* __restrict__ addend,
                           int mode, float* __restrict__ dst,
                           unsigned short* __restrict__ ph, unsigned short* __restrict__ pl) {
  reduce_body_t<NSPLIT>(blockIdx.x, part, MN, N, vecB, addend, mode, dst, ph, pl);
}

// ---------------- big GEMM: split-K partials, 256-col tiles, split-bf16 MFMA -------------
// Round-16 deltas on the round-15 kernel (both confined here):
//  (a) LDS XOR swizzle idx(r,c) = r*260 + (c ^ (((r>>3)&1)<<4). Read banks: 4j +
//      ((col+16n) ^ 16*(g&1)) -> g even / g odd use disjoint 16-bank halves, 2 g's per
//      half = 2-way (free, m136) vs previous 4-way (1.58x). Staging b128 writes keep
//      16B alignment (XOR flips dword-index bit 4 only).
//  (b) hi/lo conversion via v_cvt_pk_bf16_f32 (6 VALU per 2 elems vs ~14). Split is
//      self-correcting: lo = rne(s - actual hif), so hi's rounding mode is irrelevant.
__global__ __launch_bounds__(256, 2) void k_gemm_big(const unsigned short* __restrict__ zpkh,
                                                     const unsigned short* __restrict__ zpkl,
                                                     const float* __restrict__ Ws,
                                                     float* __restrict__ part2) {
  __shared__ float lds[2][32 * 260];   // 66,560 B
  const int t   = threadIdx.x;
  const int l   = t & 63;
  const int w   = t >> 6;              // wave 0..3
  const int col = l & 15;
  const int g   = l >> 4;              // k-chunk g*8..g*8+7
  const int c0  = (blockIdx.x < 196) ? blockIdx.x * 256 : (V_ - 256);
  const int kbase = blockIdx.y * 512;
  const int xr  = (g & 1) << 4;        // read-side XOR key (row g*8+j -> key g&1)

  f32x4 acc[4][4];  // [n][m]
#pragma unroll
  for (int n = 0; n < 4; ++n)
#pragma unroll
    for (int m = 0; m < 4; ++m) acc[n][m] = (f32x4){0.f, 0.f, 0.f, 0.f};

  // prologue: stage tile 0. wave w stages rows w+4i (i=0..7); lane covers cols 4l..4l+3.
  {
    f32x4a gg[8];
#pragma unroll
    for (int i = 0; i < 8; ++i) {
      const int r = w + 4 * i;
      gg[i] = *(const f32x4a*)(Ws + (size_t)(kbase + r) * V_ + c0 + 4 * l);
    }
#pragma unroll
    for (int i = 0; i < 8; ++i) {
      const int r = w + 4 * i;
      *(f32x4*)&lds[0][r * 260 + ((4 * l) ^ (((r >> 3) & 1) << 4))] = (f32x4)gg[i];
    }
  }
  __syncthreads();

  for (int tt = 0; tt < 16; ++tt) {
    const int buf = tt & 1;
    const int tg  = (kbase >> 5) + tt;

    // z-fragments first (oldest): coalesced 16B/lane from zpack; compute's counted-vmcnt
    // wait for them leaves the Ws loads in flight.
    bf16x8 ah[4], al[4];
#pragma unroll
    for (int m = 0; m < 4; ++m) {
      const int zb = ((tg * 4 + m) * 64 + l) * 8;
      ah[m] = *(const bf16x8*)(zpkh + zb);
      al[m] = *(const bf16x8*)(zpkl + zb);
    }

    // next Ws tile -> registers (1 KB contiguous per wave-instruction)
    f32x4a gg[8];
    if (tt + 1 < 16) {
      const float* wb = Ws + (size_t)(kbase + (tt + 1) * 32) * V_ + c0 + 4 * l;
#pragma unroll
      for (int i = 0; i < 8; ++i)
        gg[i] = *(const f32x4a*)(wb + (size_t)(w + 4 * i) * V_);
    }
    __builtin_amdgcn_sched_barrier(0);

    // compute tile tt from lds[buf]
#pragma unroll
    for (int n = 0; n < 4; ++n) {
      const int cread = w * 64 + n * 16 + col;
      float f[8];
#pragma unroll
      for (int j = 0; j < 8; ++j)
        f[j] = lds[buf][(g * 8 + j) * 260 + (cread ^ xr)];

      union { bf16x8 v; unsigned u[4]; } bh, bl;
#pragma unroll
      for (int j = 0; j < 4; ++j) {
        unsigned h = cvtpk(f[2 * j], f[2 * j + 1]);
        float h0f = __uint_as_float(h << 16);
        float h1f = __uint_as_float(h & 0xFFFF0000u);
        bh.u[j] = h;
        bl.u[j] = cvtpk(f[2 * j] - h0f, f[2 * j + 1] - h1f);
      }
#pragma unroll
      for (int m = 0; m < 4; ++m) acc[n][m] = __builtin_amdgcn_mfma_f32_16x16x32_bf16(ah[m], bh.v, acc[n][m], 0, 0, 0);
#pragma unroll
      for (int m = 0; m < 4; ++m) acc[n][m] = __builtin_amdgcn_mfma_f32_16x16x32_bf16(ah[m], bl.v, acc[n][m], 0, 0, 0);
#pragma unroll
      for (int m = 0; m < 4; ++m) acc[n][m] = __builtin_amdgcn_mfma_f32_16x16x32_bf16(al[m], bh.v, acc[n][m], 0, 0, 0);
    }
    __builtin_amdgcn_sched_barrier(0);

    // write next tile to the other buffer (b128, 16B-aligned, swizzled)
    if (tt + 1 < 16) {
#pragma unroll
      for (int i = 0; i < 8; ++i) {
        const int r = w + 4 * i;
        *(f32x4*)&lds[buf ^ 1][r * 260 + ((4 * l) ^ (((r >> 3) & 1) << 4))] = (f32x4)gg[i];
      }
    }
    __syncthreads();
  }

  float* pout = part2 + (size_t)blockIdx.y * ((size_t)64 * V_);
#pragma unroll
  for (int n = 0; n < 4; ++n) {
    const int c = c0 + w * 64 + n * 16 + col;
#pragma unroll
    for (int m = 0; m < 4; ++m)
#pragma unroll
      for (int i = 0; i < 4; ++i)
        pout[(size_t)(m * 16 + g * 4 + i) * V_ + c] = acc[n][m][i];
  }
}

// ---------------- softmax over rows (reads split-K partials + bias directly) -------------
#define SM_CHUNK 12565  // 4 * 12565 >= V_

__global__ void k_softmax1(const float* __restrict__ part2, const float* __restrict__ bs,
                           float2* __restrict__ stats) {
  __shared__ float smx[4], ssum[4];
  const int r = blockIdx.x >> 2, q = blockIdx.x & 3;
  const int beg = q * SM_CHUNK;
  const int end = (beg + SM_CHUNK < V_) ? beg + SM_CHUNK : V_;
  const float* p0 = part2 + (size_t)r * V_;
  const float* p1 = part2 + (size_t)64 * V_ + (size_t)r * V_;

  float mx = -3.4e38f;
  for (int i = beg + threadIdx.x; i < end; i += 256) mx = fmaxf(mx, p0[i] + p1[i] + bs[i]);
  mx = waveMax(mx);
  if ((threadIdx.x & 63) == 0) smx[threadIdx.x >> 6] = mx;
  __syncthreads();
  mx = fmaxf(fmaxf(smx[0], smx[1]), fmaxf(smx[2], smx[3]));

  float s = 0.f;
  for (int i = beg + threadIdx.x; i < end; i += 256) s += __expf(p0[i] + p1[i] + bs[i] - mx);
  s = waveSum(s);
  if ((threadIdx.x & 63) == 0) ssum[threadIdx.x >> 6] = s;
  __syncthreads();
  s = (ssum[0] + ssum[1]) + (ssum[2] + ssum[3]);

  if (threadIdx.x == 0) stats[blockIdx.x] = make_float2(mx, s);
}

__global__ void k_softmax2(const float* __restrict__ part2, const float* __restrict__ bs,
                           const float2* __restrict__ stats, float* __restrict__ out) {
  const int r = blockIdx.x >> 2, q = blockIdx.x & 3;
  float2 s0 = stats[r * 4 + 0], s1 = stats[r * 4 + 1];
  float2 s2 = stats[r * 4 + 2], s3 = stats[r * 4 + 3];
  float M = fmaxf(fmaxf(s0.x, s1.x), fmaxf(s2.x, s3.x));
  float S = s0.y * __expf(s0.x - M) + s1.y * __expf(s1.x - M)
          + s2.y * __expf(s2.x - M) + s3.y * __expf(s3.x - M);
  float inv = 1.f / S;
  const int beg = q * SM_CHUNK;
  const int end = (beg + SM_CHUNK < V_) ? beg + SM_CHUNK : V_;
  const float* p0 = part2 + (size_t)r * V_;
  const float* p1 = part2 + (size_t)64 * V_ + (size_t)r * V_;
  float* orow = out + (size_t)r * V_;
  for (int i = beg + threadIdx.x; i < end; i += 256)
    orow[i] = __expf(p0[i] + p1[i] + bs[i] - M) * inv;
}

// ---------------- launch ----------------
extern "C" void kernel_launch(void* const* d_in, const int* in_sizes, int n_in,
                              void* d_out, int out_size, void* d_ws, size_t ws_size,
                              hipStream_t stream) {
  const float* eh   = (const float*)d_in[0];
  const int*   ques = (const int*)d_in[1];
  const void*  mask = d_in[2];
  const float* emb  = (const float*)d_in[3];
  const float* W1   = (const float*)d_in[4];
  const float* b1   = (const float*)d_in[5];
  const float* W2   = (const float*)d_in[6];
  const float* b2   = (const float*)d_in[7];
  const float* A    = (const float*)d_in[8];
  const float* H    = (const float*)d_in[9];
  const float* Ws   = (const float*)d_in[10];
  const float* bs   = (const float*)d_in[11];
  float* out = (float*)d_out;
  char* ws = (char*)d_ws;

  float*          gpart   = (float*)(ws + 0);           // max 8,388,608
  float*          entpart = (float*)(ws + 12866048);    // 2,097,152
  float*          entsum  = (float*)(ws + 14963200);    // 4,096
  float*          hbuf    = (float*)(ws + 14967296);    // 524,288
  float*          qbuf    = (float*)(ws + 15491584);    // 262,144
  float*          ubuf    = (float*)(ws + 15753728);    // 262,144
  unsigned short* zpkh    = (unsigned short*)(ws + 16015872);  // 131,072
  unsigned short* zpkl    = (unsigned short*)(ws + 16146944);  // 131,072
  float2*         stats   = (float2*)(ws + 16278016);   // 2,048
  float*          part2   = (float*)(ws + 20971520);    // 25,731,584

  // P1..P8 as one cooperative launch (512 blocks x 256 thr, 8 phases, grid.sync).
  {
    const float* a_eh = eh; const void* a_mask = mask; float* a_entpart = entpart;
    const int* a_ques = ques; const float* a_emb = emb; const float* a_W1 = W1;
    float* a_gpart = gpart; float* a_entsum = entsum; const float* a_b1 = b1;
    float* a_hbuf = hbuf; const float* a_W2 = W2; const float* a_b2 = b2;
    float* a_qbuf = qbuf; const float* a_A = A; float* a_ubuf = ubuf;
    const float* a_H = H; unsigned short* a_zpkh = zpkh; unsigned short* a_zpkl = zpkl;
    void* args[] = {&a_eh, &a_mask, &a_entpart, &a_ques, &a_emb, &a_W1, &a_gpart,
                    &a_entsum, &a_b1, &a_hbuf, &a_W2, &a_b2, &a_qbuf, &a_A, &a_ubuf,
                    &a_H, &a_zpkh, &a_zpkl};
    hipError_t ce = hipLaunchCooperativeKernel((void*)k_chain, dim3(512), dim3(256),
                                               args, 0, stream);
    if (ce != hipSuccess) {
      // deterministic fallback: round-15 separate launches
      k_p1<<<1024, 256, 0, stream>>>(eh, mask, entpart, ques, emb, W1, gpart);
      k_p2<<<516, 256, 0, stream>>>(entpart, entsum, gpart, b1, hbuf);
      k_gemm64<<<dim3(16, 32), 256, 0, stream>>>(hbuf, W2, 2048, 1024, 64, gpart);
      k_reduce_t<32><<<256, 256, 0, stream>>>(gpart, 64 * 1024, 1024, b2, nullptr, 2, qbuf, nullptr, nullptr);
      k_gemm64<<<dim3(16, 16), 256, 0, stream>>>(qbuf, A, 1024, 1024, 64, gpart);
      k_reduce_t<16><<<256, 256, 0, stream>>>(gpart, 64 * 1024, 1024, entsum, nullptr, 3, ubuf, nullptr, nullptr);
      k_gemm64<<<dim3(16, 16), 256, 0, stream>>>(ubuf, H, 1024, 1024, 64, gpart);
      k_reduce_t<16><<<256, 256, 0, stream>>>(gpart, 64 * 1024, 1024, nullptr, qbuf, 4, nullptr, zpkh, zpkl);
    }
  }

  // P9: split-K partials = z @ Ws  [64,V]x2, 256-col tiles, 394 blocks
  k_gemm_big<<<dim3(197, 2), 256, 0, stream>>>(zpkh, zpkl, Ws, part2);

  // P10/P11: softmax two-pass over (p0+p1+bs)
  k_softmax1<<<256, 256, 0, stream>>>(part2, bs, stats);
  k_softmax2<<<256, 256, 0, stream>>>(part2, bs, stats, out);

  (void)in_sizes; (void)n_in; (void)out_size; (void)ws_size;
}

// Round 17
// 251.685 us; speedup vs baseline: 2.7056x; 2.7056x over previous
//
#include <hip/hip_runtime.h>
#include <stdint.h>

#define V_ 50257
#define D_ 1024
#define F_ 2048
#define B_ 64
#define E_ 512
#define ROWS_ (B_*E_)

typedef __attribute__((ext_vector_type(8))) short bf16x8;
typedef __attribute__((ext_vector_type(4))) float f32x4;
typedef __attribute__((ext_vector_type(4), aligned(4))) float f32x4a;  // 4B-aligned global loads

__device__ __forceinline__ unsigned rne1(float a) {
  unsigned u = __float_as_uint(a);
  return (u + 0x7FFFu + ((u >> 16) & 1u)) >> 16;
}

// packed bf16 convert: r = bf16(a) | bf16(b)<<16, 1 VALU op per pair.
// hi rounding mode is irrelevant for the split (lo = rne(s - ACTUAL hif) self-corrects).
__device__ __forceinline__ unsigned cvtpk(float a, float b) {
  unsigned r;
  asm("v_cvt_pk_bf16_f32 %0, %1, %2" : "=v"(r) : "v"(a), "v"(b));
  return r;
}

__device__ __forceinline__ float waveMax(float v) {
#pragma unroll
  for (int o = 32; o > 0; o >>= 1) v = fmaxf(v, __shfl_xor(v, o, 64));
  return v;
}
__device__ __forceinline__ float waveSum(float v) {
#pragma unroll
  for (int o = 32; o > 0; o >>= 1) v += __shfl_xor(v, o, 64);
  return v;
}

// ---------------- device bodies (round-15 proven) ----------------

__device__ __forceinline__ void ent_partial_body(int bid, const float* __restrict__ eh,
                                                 const void* __restrict__ mask,
                                                 float* __restrict__ part) {
  __shared__ int s_mode;
  const int tid = threadIdx.x;
  const uint32_t* mu = (const uint32_t*)mask;
  int f = 0;
  for (int i = tid; i < (ROWS_ / 4); i += 256) {
    uint32_t u = mu[i];
    if (u == 0x3F800000u) f |= 2;
    else if (u & 0xFFFFFF00u) f |= 1;
  }
  if (tid == 0) s_mode = 0;
  __syncthreads();
  if (f) atomicOr(&s_mode, f);
  __syncthreads();
  const int sm = s_mode;
  const int mode = (sm & 1) ? 1 : ((sm & 2) ? 2 : 0);

  float4 acc = make_float4(0.f, 0.f, 0.f, 0.f);
  const float4* eh4 = (const float4*)eh;
  for (int row = bid; row < ROWS_; row += 512) {
    bool on;
    if (mode == 1)      on = ((const unsigned char*)mask)[row] != 0;
    else if (mode == 2) on = ((const float*)mask)[row] != 0.f;
    else                on = ((const int*)mask)[row] != 0;
    if (on) {
      float4 v = eh4[(size_t)row * (D_ / 4) + tid];
      acc.x += v.x; acc.y += v.y; acc.z += v.z; acc.w += v.w;
    }
  }
  ((float4*)part)[(size_t)bid * (D_ / 4) + tid] = acc;
}

__device__ __forceinline__ void ent_reduce_body(int bid, const float* __restrict__ part,
                                                float* __restrict__ entsum) {
  int d = bid * 256 + threadIdx.x;
  float s0 = 0.f, s1 = 0.f, s2 = 0.f, s3 = 0.f;
#pragma unroll 8
  for (int i = 0; i < 512; i += 4) {
    s0 += part[(size_t)(i    ) * D_ + d];
    s1 += part[(size_t)(i + 1) * D_ + d];
    s2 += part[(size_t)(i + 2) * D_ + d];
    s3 += part[(size_t)(i + 3) * D_ + d];
  }
  entsum[d] = (s0 + s1) + (s2 + s3);
}

__device__ __forceinline__ void gemm64_body(int bx, int by, const float* __restrict__ X,
                                            const int* __restrict__ gatherIdx,
                                            const float* __restrict__ emb,
                                            const float* __restrict__ W,
                                            int K, int N, int KB, float* __restrict__ part) {
  const int l  = threadIdx.x & 63;
  const int rg = __builtin_amdgcn_readfirstlane((int)(threadIdx.x >> 6));
  const int c  = bx * 64 + l;
  const int k0 = by * KB;
  const int m0 = rg * 16;

  const float* Xp = gatherIdx ? emb : X;
  int rb[16];
#pragma unroll
  for (int r = 0; r < 16; ++r) {
    int m = m0 + r;
    rb[r] = gatherIdx ? gatherIdx[m] * K : m * K;
  }

  float acc[16];
#pragma unroll
  for (int r = 0; r < 16; ++r) acc[r] = 0.f;

  for (int k = k0; k < k0 + KB; k += 8) {
    float wv[8];
#pragma unroll
    for (int j = 0; j < 8; ++j) wv[j] = W[(size_t)(k + j) * N + c];
#pragma unroll
    for (int r = 0; r < 16; ++r) {
      float4 x0 = *(const float4*)&Xp[rb[r] + k];
      float4 x1 = *(const float4*)&Xp[rb[r] + k + 4];
      acc[r] = fmaf(x0.x, wv[0], acc[r]);
      acc[r] = fmaf(x0.y, wv[1], acc[r]);
      acc[r] = fmaf(x0.z, wv[2], acc[r]);
      acc[r] = fmaf(x0.w, wv[3], acc[r]);
      acc[r] = fmaf(x1.x, wv[4], acc[r]);
      acc[r] = fmaf(x1.y, wv[5], acc[r]);
      acc[r] = fmaf(x1.z, wv[6], acc[r]);
      acc[r] = fmaf(x1.w, wv[7], acc[r]);
    }
  }
  size_t base = (size_t)by * ((size_t)64 * N);
#pragma unroll
  for (int r = 0; r < 16; ++r) part[base + (size_t)(m0 + r) * N + c] = acc[r];
}

// reduce split-K partials + epilogue, compile-time NSPLIT.
// mode 1: relu(x+vecB[c]); 2: x+vecB[c]; 3: x*vecB[c];
// mode 4: idx is zpack DEST index; gathers src, writes bf16 hi/lo in MFMA-fragment order.
template<int NSPLIT>
__device__ __forceinline__ void reduce_body_t(int bid, const float* __restrict__ part,
                                              int MN, int N,
                                              const float* __restrict__ vecB,
                                              const float* __restrict__ addend,
                                              int mode, float* __restrict__ dst,
                                              unsigned short* __restrict__ ph,
                                              unsigned short* __restrict__ pl) {
  int idx = bid * 256 + threadIdx.x;
  if (idx >= MN) return;

  if (mode == 4) {
    const int d   = idx;
    const int j   = d & 7;
    const int l   = (d >> 3) & 63;
    const int m   = (d >> 9) & 3;
    const int tg  = d >> 11;
    const int col = l & 15;
    const int g   = l >> 4;
    const int row = m * 16 + col;
    const int kk  = tg * 32 + g * 8 + j;
    const int src = row * 1024 + kk;
    float s = 0.f;
#pragma unroll
    for (int i = 0; i < NSPLIT; ++i) s += part[(size_t)i * MN + src];
    s += addend[src];
    unsigned hi = rne1(s);
    float hif = __uint_as_float(hi << 16);
    ph[d] = (unsigned short)hi;
    pl[d] = (unsigned short)rne1(s - hif);
    return;
  }

  float s = 0.f;
#pragma unroll
  for (int i = 0; i < NSPLIT; ++i) s += part[(size_t)i * MN + idx];
  int c = idx & (N - 1);
  if (mode == 1)      { s += vecB[c]; s = s > 0.f ? s : 0.f; dst[idx] = s; }
  else if (mode == 2) { s += vecB[c]; dst[idx] = s; }
  else                { s *= vecB[c]; dst[idx] = s; }
}

// ---------------- phase kernels (round-15 proven separate launches) ----------------
__global__ void k_p1(const float* __restrict__ eh, const void* __restrict__ mask,
                     float* __restrict__ entpart, const int* __restrict__ ques,
                     const float* __restrict__ emb, const float* __restrict__ W1,
                     float* __restrict__ gpart) {
  int bid = blockIdx.x;
  if (bid < 512) ent_partial_body(bid, eh, mask, entpart);
  else {
    int b2 = bid - 512;
    gemm64_body(b2 & 31, b2 >> 5, nullptr, ques, emb, W1, 1024, 2048, 64, gpart);
  }
}

__global__ void k_p2(const float* __restrict__ entpart, float* __restrict__ entsum,
                     const float* __restrict__ gpart, const float* __restrict__ b1,
                     float* __restrict__ hbuf) {
  int bid = blockIdx.x;
  if (bid < 4) ent_reduce_body(bid, entpart, entsum);
  else reduce_body_t<16>(bid - 4, gpart, 64 * 2048, 2048, b1, nullptr, 1, hbuf, nullptr, nullptr);
}

__global__ void k_gemm64(const float* __restrict__ X, const float* __restrict__ W,
                         int K, int N, int KB, float* __restrict__ part) {
  gemm64_body(blockIdx.x, blockIdx.y, X, nullptr, nullptr, W, K, N, KB, part);
}

template<int NSPLIT>
__global__ void k_reduce_t(const float* __restrict__ part, int MN, int N,
                           const float* __restrict__ vecB, const float* __restrict__ addend,
                           int mode, float* __restrict__ dst,
                           unsigned short* __restrict__ ph, unsigned short* __restrict__ pl) {
  reduce_body_t<NSPLIT>(blockIdx.x, part, MN, N, vecB, addend, mode, dst, ph, pl);
}

// ---------------- big GEMM: split-K partials, 256-col tiles, split-bf16 MFMA -------------
// Round-16's measured-better inner loop kept (both changes confined here):
//  (a) LDS XOR swizzle idx(r,c) = r*260 + (c ^ (((r>>3)&1)<<4)): read banks for g even /
//      g odd land in disjoint 16-bank halves -> 2-way (free, m136) vs 4-way (1.58x).
//      Staging b128 writes keep 16B alignment (XOR flips dword-index bit 4 only).
//  (b) hi/lo conversion via v_cvt_pk_bf16_f32 (~6 VALU per 2 elems vs ~14). Split is
//      self-correcting: lo = rne(s - actual hif), so hi's rounding mode is irrelevant.
// Structure otherwise round-15: 394 blocks (197 col x 2 K-halves), reg-staged f32x4 +
// ds_write_b128 + sched_barrier, zpack'd coalesced z-fragments, __syncthreads drain.
__global__ __launch_bounds__(256, 2) void k_gemm_big(const unsigned short* __restrict__ zpkh,
                                                     const unsigned short* __restrict__ zpkl,
                                                     const float* __restrict__ Ws,
                                                     float* __restrict__ part2) {
  __shared__ float lds[2][32 * 260];   // 66,560 B
  const int t   = threadIdx.x;
  const int l   = t & 63;
  const int w   = t >> 6;              // wave 0..3
  const int col = l & 15;
  const int g   = l >> 4;              // k-chunk g*8..g*8+7
  const int c0  = (blockIdx.x < 196) ? blockIdx.x * 256 : (V_ - 256);
  const int kbase = blockIdx.y * 512;
  const int xr  = (g & 1) << 4;        // read-side XOR key

  f32x4 acc[4][4];  // [n][m]
#pragma unroll
  for (int n = 0; n < 4; ++n)
#pragma unroll
    for (int m = 0; m < 4; ++m) acc[n][m] = (f32x4){0.f, 0.f, 0.f, 0.f};

  // prologue: stage tile 0. wave w stages rows w+4i (i=0..7); lane covers cols 4l..4l+3.
  {
    f32x4a gg[8];
#pragma unroll
    for (int i = 0; i < 8; ++i) {
      const int r = w + 4 * i;
      gg[i] = *(const f32x4a*)(Ws + (size_t)(kbase + r) * V_ + c0 + 4 * l);
    }
#pragma unroll
    for (int i = 0; i < 8; ++i) {
      const int r = w + 4 * i;
      *(f32x4*)&lds[0][r * 260 + ((4 * l) ^ (((r >> 3) & 1) << 4))] = (f32x4)gg[i];
    }
  }
  __syncthreads();

  for (int tt = 0; tt < 16; ++tt) {
    const int buf = tt & 1;
    const int tg  = (kbase >> 5) + tt;

    // z-fragments first (oldest): coalesced 16B/lane from zpack; compute's counted-vmcnt
    // wait for them leaves the Ws loads in flight.
    bf16x8 ah[4], al[4];
#pragma unroll
    for (int m = 0; m < 4; ++m) {
      const int zb = ((tg * 4 + m) * 64 + l) * 8;
      ah[m] = *(const bf16x8*)(zpkh + zb);
      al[m] = *(const bf16x8*)(zpkl + zb);
    }

    // next Ws tile -> registers (1 KB contiguous per wave-instruction)
    f32x4a gg[8];
    if (tt + 1 < 16) {
      const float* wb = Ws + (size_t)(kbase + (tt + 1) * 32) * V_ + c0 + 4 * l;
#pragma unroll
      for (int i = 0; i < 8; ++i)
        gg[i] = *(const f32x4a*)(wb + (size_t)(w + 4 * i) * V_);
    }
    __builtin_amdgcn_sched_barrier(0);

    // compute tile tt from lds[buf]
#pragma unroll
    for (int n = 0; n < 4; ++n) {
      const int cread = w * 64 + n * 16 + col;
      float f[8];
#pragma unroll
      for (int j = 0; j < 8; ++j)
        f[j] = lds[buf][(g * 8 + j) * 260 + (cread ^ xr)];

      union { bf16x8 v; unsigned u[4]; } bh, bl;
#pragma unroll
      for (int j = 0; j < 4; ++j) {
        unsigned h = cvtpk(f[2 * j], f[2 * j + 1]);
        float h0f = __uint_as_float(h << 16);
        float h1f = __uint_as_float(h & 0xFFFF0000u);
        bh.u[j] = h;
        bl.u[j] = cvtpk(f[2 * j] - h0f, f[2 * j + 1] - h1f);
      }
#pragma unroll
      for (int m = 0; m < 4; ++m) acc[n][m] = __builtin_amdgcn_mfma_f32_16x16x32_bf16(ah[m], bh.v, acc[n][m], 0, 0, 0);
#pragma unroll
      for (int m = 0; m < 4; ++m) acc[n][m] = __builtin_amdgcn_mfma_f32_16x16x32_bf16(ah[m], bl.v, acc[n][m], 0, 0, 0);
#pragma unroll
      for (int m = 0; m < 4; ++m) acc[n][m] = __builtin_amdgcn_mfma_f32_16x16x32_bf16(al[m], bh.v, acc[n][m], 0, 0, 0);
    }
    __builtin_amdgcn_sched_barrier(0);

    // write next tile to the other buffer (b128, 16B-aligned, swizzled)
    if (tt + 1 < 16) {
#pragma unroll
      for (int i = 0; i < 8; ++i) {
        const int r = w + 4 * i;
        *(f32x4*)&lds[buf ^ 1][r * 260 + ((4 * l) ^ (((r >> 3) & 1) << 4))] = (f32x4)gg[i];
      }
    }
    __syncthreads();
  }

  float* pout = part2 + (size_t)blockIdx.y * ((size_t)64 * V_);
#pragma unroll
  for (int n = 0; n < 4; ++n) {
    const int c = c0 + w * 64 + n * 16 + col;
#pragma unroll
    for (int m = 0; m < 4; ++m)
#pragma unroll
      for (int i = 0; i < 4; ++i)
        pout[(size_t)(m * 16 + g * 4 + i) * V_ + c] = acc[n][m][i];
  }
}

// ---------------- softmax over rows (reads split-K partials + bias directly) -------------
#define SM_CHUNK 12565  // 4 * 12565 >= V_

__global__ void k_softmax1(const float* __restrict__ part2, const float* __restrict__ bs,
                           float2* __restrict__ stats) {
  __shared__ float smx[4], ssum[4];
  const int r = blockIdx.x >> 2, q = blockIdx.x & 3;
  const int beg = q * SM_CHUNK;
  const int end = (beg + SM_CHUNK < V_) ? beg + SM_CHUNK : V_;
  const float* p0 = part2 + (size_t)r * V_;
  const float* p1 = part2 + (size_t)64 * V_ + (size_t)r * V_;

  float mx = -3.4e38f;
  for (int i = beg + threadIdx.x; i < end; i += 256) mx = fmaxf(mx, p0[i] + p1[i] + bs[i]);
  mx = waveMax(mx);
  if ((threadIdx.x & 63) == 0) smx[threadIdx.x >> 6] = mx;
  __syncthreads();
  mx = fmaxf(fmaxf(smx[0], smx[1]), fmaxf(smx[2], smx[3]));

  float s = 0.f;
  for (int i = beg + threadIdx.x; i < end; i += 256) s += __expf(p0[i] + p1[i] + bs[i] - mx);
  s = waveSum(s);
  if ((threadIdx.x & 63) == 0) ssum[threadIdx.x >> 6] = s;
  __syncthreads();
  s = (ssum[0] + ssum[1]) + (ssum[2] + ssum[3]);

  if (threadIdx.x == 0) stats[blockIdx.x] = make_float2(mx, s);
}

__global__ void k_softmax2(const float* __restrict__ part2, const float* __restrict__ bs,
                           const float2* __restrict__ stats, float* __restrict__ out) {
  const int r = blockIdx.x >> 2, q = blockIdx.x & 3;
  float2 s0 = stats[r * 4 + 0], s1 = stats[r * 4 + 1];
  float2 s2 = stats[r * 4 + 2], s3 = stats[r * 4 + 3];
  float M = fmaxf(fmaxf(s0.x, s1.x), fmaxf(s2.x, s3.x));
  float S = s0.y * __expf(s0.x - M) + s1.y * __expf(s1.x - M)
          + s2.y * __expf(s2.x - M) + s3.y * __expf(s3.x - M);
  float inv = 1.f / S;
  const int beg = q * SM_CHUNK;
  const int end = (beg + SM_CHUNK < V_) ? beg + SM_CHUNK : V_;
  const float* p0 = part2 + (size_t)r * V_;
  const float* p1 = part2 + (size_t)64 * V_ + (size_t)r * V_;
  float* orow = out + (size_t)r * V_;
  for (int i = beg + threadIdx.x; i < end; i += 256)
    orow[i] = __expf(p0[i] + p1[i] + bs[i] - M) * inv;
}

// ---------------- launch ----------------
extern "C" void kernel_launch(void* const* d_in, const int* in_sizes, int n_in,
                              void* d_out, int out_size, void* d_ws, size_t ws_size,
                              hipStream_t stream) {
  const float* eh   = (const float*)d_in[0];
  const int*   ques = (const int*)d_in[1];
  const void*  mask = d_in[2];
  const float* emb  = (const float*)d_in[3];
  const float* W1   = (const float*)d_in[4];
  const float* b1   = (const float*)d_in[5];
  const float* W2   = (const float*)d_in[6];
  const float* b2   = (const float*)d_in[7];
  const float* A    = (const float*)d_in[8];
  const float* H    = (const float*)d_in[9];
  const float* Ws   = (const float*)d_in[10];
  const float* bs   = (const float*)d_in[11];
  float* out = (float*)d_out;
  char* ws = (char*)d_ws;

  float*          gpart   = (float*)(ws + 0);           // max 8,388,608
  float*          entpart = (float*)(ws + 12866048);    // 2,097,152
  float*          entsum  = (float*)(ws + 14963200);    // 4,096
  float*          hbuf    = (float*)(ws + 14967296);    // 524,288
  float*          qbuf    = (float*)(ws + 15491584);    // 262,144
  float*          ubuf    = (float*)(ws + 15753728);    // 262,144
  unsigned short* zpkh    = (unsigned short*)(ws + 16015872);  // 131,072
  unsigned short* zpkl    = (unsigned short*)(ws + 16146944);  // 131,072
  float2*         stats   = (float2*)(ws + 16278016);   // 2,048
  float*          part2   = (float*)(ws + 20971520);    // 25,731,584

  // P1: ent_partial (512 blocks) || h-gemm partials (512 blocks)
  k_p1<<<1024, 256, 0, stream>>>(eh, mask, entpart, ques, emb, W1, gpart);
  // P2: ent_reduce (4) || h = relu(.+b1) (512)
  k_p2<<<516, 256, 0, stream>>>(entpart, entsum, gpart, b1, hbuf);

  // P3/P4: q = h @ W2 + b2                 [64,1024], K=2048, split 32
  k_gemm64<<<dim3(16, 32), 256, 0, stream>>>(hbuf, W2, 2048, 1024, 64, gpart);
  k_reduce_t<32><<<256, 256, 0, stream>>>(gpart, 64 * 1024, 1024, b2, nullptr, 2, qbuf, nullptr, nullptr);

  // P5/P6: u = (q @ A) * ent_sum           [64,1024], split 16
  k_gemm64<<<dim3(16, 16), 256, 0, stream>>>(qbuf, A, 1024, 1024, 64, gpart);
  k_reduce_t<16><<<256, 256, 0, stream>>>(gpart, 64 * 1024, 1024, entsum, nullptr, 3, ubuf, nullptr, nullptr);

  // P7/P8: z = q + u @ H -> zpack bf16 hi/lo (MFMA-fragment order), split 16
  k_gemm64<<<dim3(16, 16), 256, 0, stream>>>(ubuf, H, 1024, 1024, 64, gpart);
  k_reduce_t<16><<<256, 256, 0, stream>>>(gpart, 64 * 1024, 1024, nullptr, qbuf, 4, nullptr, zpkh, zpkl);

  // P9: split-K partials = z @ Ws  [64,V]x2, 256-col tiles, 394 blocks
  k_gemm_big<<<dim3(197, 2), 256, 0, stream>>>(zpkh, zpkl, Ws, part2);

  // P10/P11: softmax two-pass over (p0+p1+bs)
  k_softmax1<<<256, 256, 0, stream>>>(part2, bs, stats);
  k_softmax2<<<256, 256, 0, stream>>>(part2, bs, stats, out);

  (void)in_sizes; (void)n_in; (void)out_size; (void)ws_size;
}

// Round 18
// 250.943 us; speedup vs baseline: 2.7136x; 1.0030x over previous
//
#include <hip/hip_runtime.h>
#include <stdint.h>

#define V_ 50257
#define D_ 1024
#define F_ 2048
#define B_ 64
#define E_ 512
#define ROWS_ (B_*E_)

typedef __attribute__((ext_vector_type(8))) short bf16x8;
typedef __attribute__((ext_vector_type(4))) float f32x4;
typedef __attribute__((ext_vector_type(4), aligned(4))) float f32x4a;  // 4B-aligned global loads

__device__ __forceinline__ unsigned rne1(float a) {
  unsigned u = __float_as_uint(a);
  return (u + 0x7FFFu + ((u >> 16) & 1u)) >> 16;
}

// packed bf16 convert: r = bf16(a) | bf16(b)<<16, 1 VALU op per pair.
// hi rounding mode is irrelevant for the split (lo = rne(s - ACTUAL hif) self-corrects).
__device__ __forceinline__ unsigned cvtpk(float a, float b) {
  unsigned r;
  asm("v_cvt_pk_bf16_f32 %0, %1, %2" : "=v"(r) : "v"(a), "v"(b));
  return r;
}

__device__ __forceinline__ float waveMax(float v) {
#pragma unroll
  for (int o = 32; o > 0; o >>= 1) v = fmaxf(v, __shfl_xor(v, o, 64));
  return v;
}
__device__ __forceinline__ float waveSum(float v) {
#pragma unroll
  for (int o = 32; o > 0; o >>= 1) v += __shfl_xor(v, o, 64);
  return v;
}

// ---------------- device bodies (round-15 proven) ----------------

__device__ __forceinline__ void ent_partial_body(int bid, const float* __restrict__ eh,
                                                 const void* __restrict__ mask,
                                                 float* __restrict__ part) {
  __shared__ int s_mode;
  const int tid = threadIdx.x;
  const uint32_t* mu = (const uint32_t*)mask;
  int f = 0;
  for (int i = tid; i < (ROWS_ / 4); i += 256) {
    uint32_t u = mu[i];
    if (u == 0x3F800000u) f |= 2;
    else if (u & 0xFFFFFF00u) f |= 1;
  }
  if (tid == 0) s_mode = 0;
  __syncthreads();
  if (f) atomicOr(&s_mode, f);
  __syncthreads();
  const int sm = s_mode;
  const int mode = (sm & 1) ? 1 : ((sm & 2) ? 2 : 0);

  float4 acc = make_float4(0.f, 0.f, 0.f, 0.f);
  const float4* eh4 = (const float4*)eh;
  for (int row = bid; row < ROWS_; row += 512) {
    bool on;
    if (mode == 1)      on = ((const unsigned char*)mask)[row] != 0;
    else if (mode == 2) on = ((const float*)mask)[row] != 0.f;
    else                on = ((const int*)mask)[row] != 0;
    if (on) {
      float4 v = eh4[(size_t)row * (D_ / 4) + tid];
      acc.x += v.x; acc.y += v.y; acc.z += v.z; acc.w += v.w;
    }
  }
  ((float4*)part)[(size_t)bid * (D_ / 4) + tid] = acc;
}

__device__ __forceinline__ void ent_reduce_body(int bid, const float* __restrict__ part,
                                                float* __restrict__ entsum) {
  int d = bid * 256 + threadIdx.x;
  float s0 = 0.f, s1 = 0.f, s2 = 0.f, s3 = 0.f;
#pragma unroll 8
  for (int i = 0; i < 512; i += 4) {
    s0 += part[(size_t)(i    ) * D_ + d];
    s1 += part[(size_t)(i + 1) * D_ + d];
    s2 += part[(size_t)(i + 2) * D_ + d];
    s3 += part[(size_t)(i + 3) * D_ + d];
  }
  entsum[d] = (s0 + s1) + (s2 + s3);
}

__device__ __forceinline__ void gemm64_body(int bx, int by, const float* __restrict__ X,
                                            const int* __restrict__ gatherIdx,
                                            const float* __restrict__ emb,
                                            const float* __restrict__ W,
                                            int K, int N, int KB, float* __restrict__ part) {
  const int l  = threadIdx.x & 63;
  const int rg = __builtin_amdgcn_readfirstlane((int)(threadIdx.x >> 6));
  const int c  = bx * 64 + l;
  const int k0 = by * KB;
  const int m0 = rg * 16;

  const float* Xp = gatherIdx ? emb : X;
  int rb[16];
#pragma unroll
  for (int r = 0; r < 16; ++r) {
    int m = m0 + r;
    rb[r] = gatherIdx ? gatherIdx[m] * K : m * K;
  }

  float acc[16];
#pragma unroll
  for (int r = 0; r < 16; ++r) acc[r] = 0.f;

  for (int k = k0; k < k0 + KB; k += 8) {
    float wv[8];
#pragma unroll
    for (int j = 0; j < 8; ++j) wv[j] = W[(size_t)(k + j) * N + c];
#pragma unroll
    for (int r = 0; r < 16; ++r) {
      float4 x0 = *(const float4*)&Xp[rb[r] + k];
      float4 x1 = *(const float4*)&Xp[rb[r] + k + 4];
      acc[r] = fmaf(x0.x, wv[0], acc[r]);
      acc[r] = fmaf(x0.y, wv[1], acc[r]);
      acc[r] = fmaf(x0.z, wv[2], acc[r]);
      acc[r] = fmaf(x0.w, wv[3], acc[r]);
      acc[r] = fmaf(x1.x, wv[4], acc[r]);
      acc[r] = fmaf(x1.y, wv[5], acc[r]);
      acc[r] = fmaf(x1.z, wv[6], acc[r]);
      acc[r] = fmaf(x1.w, wv[7], acc[r]);
    }
  }
  size_t base = (size_t)by * ((size_t)64 * N);
#pragma unroll
  for (int r = 0; r < 16; ++r) part[base + (size_t)(m0 + r) * N + c] = acc[r];
}

// reduce split-K partials + epilogue, compile-time NSPLIT.
// mode 1: relu(x+vecB[c]); 2: x+vecB[c]; 3: x*vecB[c];
// mode 4: idx is zpack DEST index; gathers src, writes bf16 hi/lo in MFMA-fragment order.
template<int NSPLIT>
__device__ __forceinline__ void reduce_body_t(int bid, const float* __restrict__ part,
                                              int MN, int N,
                                              const float* __restrict__ vecB,
                                              const float* __restrict__ addend,
                                              int mode, float* __restrict__ dst,
                                              unsigned short* __restrict__ ph,
                                              unsigned short* __restrict__ pl) {
  int idx = bid * 256 + threadIdx.x;
  if (idx >= MN) return;

  if (mode == 4) {
    const int d   = idx;
    const int j   = d & 7;
    const int l   = (d >> 3) & 63;
    const int m   = (d >> 9) & 3;
    const int tg  = d >> 11;
    const int col = l & 15;
    const int g   = l >> 4;
    const int row = m * 16 + col;
    const int kk  = tg * 32 + g * 8 + j;
    const int src = row * 1024 + kk;
    float s = 0.f;
#pragma unroll
    for (int i = 0; i < NSPLIT; ++i) s += part[(size_t)i * MN + src];
    s += addend[src];
    unsigned hi = rne1(s);
    float hif = __uint_as_float(hi << 16);
    ph[d] = (unsigned short)hi;
    pl[d] = (unsigned short)rne1(s - hif);
    return;
  }

  float s = 0.f;
#pragma unroll
  for (int i = 0; i < NSPLIT; ++i) s += part[(size_t)i * MN + idx];
  int c = idx & (N - 1);
  if (mode == 1)      { s += vecB[c]; s = s > 0.f ? s : 0.f; dst[idx] = s; }
  else if (mode == 2) { s += vecB[c]; dst[idx] = s; }
  else                { s *= vecB[c]; dst[idx] = s; }
}

// ---------------- phase kernels (round-15 proven separate launches) ----------------
__global__ void k_p1(const float* __restrict__ eh, const void* __restrict__ mask,
                     float* __restrict__ entpart, const int* __restrict__ ques,
                     const float* __restrict__ emb, const float* __restrict__ W1,
                     float* __restrict__ gpart) {
  int bid = blockIdx.x;
  if (bid < 512) ent_partial_body(bid, eh, mask, entpart);
  else {
    int b2 = bid - 512;
    gemm64_body(b2 & 31, b2 >> 5, nullptr, ques, emb, W1, 1024, 2048, 64, gpart);
  }
}

__global__ void k_p2(const float* __restrict__ entpart, float* __restrict__ entsum,
                     const float* __restrict__ gpart, const float* __restrict__ b1,
                     float* __restrict__ hbuf) {
  int bid = blockIdx.x;
  if (bid < 4) ent_reduce_body(bid, entpart, entsum);
  else reduce_body_t<16>(bid - 4, gpart, 64 * 2048, 2048, b1, nullptr, 1, hbuf, nullptr, nullptr);
}

__global__ void k_gemm64(const float* __restrict__ X, const float* __restrict__ W,
                         int K, int N, int KB, float* __restrict__ part) {
  gemm64_body(blockIdx.x, blockIdx.y, X, nullptr, nullptr, W, K, N, KB, part);
}

template<int NSPLIT>
__global__ void k_reduce_t(const float* __restrict__ part, int MN, int N,
                           const float* __restrict__ vecB, const float* __restrict__ addend,
                           int mode, float* __restrict__ dst,
                           unsigned short* __restrict__ ph, unsigned short* __restrict__ pl) {
  reduce_body_t<NSPLIT>(blockIdx.x, part, MN, N, vecB, addend, mode, dst, ph, pl);
}

// ---------------- big GEMM: split-K partials, 256-col tiles, split-bf16 MFMA -------------
// Round-16's measured-better inner loop kept (both changes confined here):
//  (a) LDS XOR swizzle idx(r,c) = r*260 + (c ^ (((r>>3)&1)<<4)): read banks for g even /
//      g odd land in disjoint 16-bank halves -> 2-way (free, m136) vs 4-way (1.58x).
//      Staging b128 writes keep 16B alignment (XOR flips dword-index bit 4 only).
//  (b) hi/lo conversion via v_cvt_pk_bf16_f32 (~6 VALU per 2 elems vs ~14). Split is
//      self-correcting: lo = rne(s - actual hif), so hi's rounding mode is irrelevant.
// Structure otherwise round-15: 394 blocks (197 col x 2 K-halves), reg-staged f32x4 +
// ds_write_b128 + sched_barrier, zpack'd coalesced z-fragments, __syncthreads drain.
__global__ __launch_bounds__(256, 2) void k_gemm_big(const unsigned short* __restrict__ zpkh,
                                                     const unsigned short* __restrict__ zpkl,
                                                     const float* __restrict__ Ws,
                                                     float* __restrict__ part2) {
  __shared__ float lds[2][32 * 260];   // 66,560 B
  const int t   = threadIdx.x;
  const int l   = t & 63;
  const int w   = t >> 6;              // wave 0..3
  const int col = l & 15;
  const int g   = l >> 4;              // k-chunk g*8..g*8+7
  const int c0  = (blockIdx.x < 196) ? blockIdx.x * 256 : (V_ - 256);
  const int kbase = blockIdx.y * 512;
  const int xr  = (g & 1) << 4;        // read-side XOR key

  f32x4 acc[4][4];  // [n][m]
#pragma unroll
  for (int n = 0; n < 4; ++n)
#pragma unroll
    for (int m = 0; m < 4; ++m) acc[n][m] = (f32x4){0.f, 0.f, 0.f, 0.f};

  // prologue: stage tile 0. wave w stages rows w+4i (i=0..7); lane covers cols 4l..4l+3.
  {
    f32x4a gg[8];
#pragma unroll
    for (int i = 0; i < 8; ++i) {
      const int r = w + 4 * i;
      gg[i] = *(const f32x4a*)(Ws + (size_t)(kbase + r) * V_ + c0 + 4 * l);
    }
#pragma unroll
    for (int i = 0; i < 8; ++i) {
      const int r = w + 4 * i;
      *(f32x4*)&lds[0][r * 260 + ((4 * l) ^ (((r >> 3) & 1) << 4))] = (f32x4)gg[i];
    }
  }
  __syncthreads();

  for (int tt = 0; tt < 16; ++tt) {
    const int buf = tt & 1;
    const int tg  = (kbase >> 5) + tt;

    // z-fragments first (oldest): coalesced 16B/lane from zpack; compute's counted-vmcnt
    // wait for them leaves the Ws loads in flight.
    bf16x8 ah[4], al[4];
#pragma unroll
    for (int m = 0; m < 4; ++m) {
      const int zb = ((tg * 4 + m) * 64 + l) * 8;
      ah[m] = *(const bf16x8*)(zpkh + zb);
      al[m] = *(const bf16x8*)(zpkl + zb);
    }

    // next Ws tile -> registers (1 KB contiguous per wave-instruction)
    f32x4a gg[8];
    if (tt + 1 < 16) {
      const float* wb = Ws + (size_t)(kbase + (tt + 1) * 32) * V_ + c0 + 4 * l;
#pragma unroll
      for (int i = 0; i < 8; ++i)
        gg[i] = *(const f32x4a*)(wb + (size_t)(w + 4 * i) * V_);
    }
    __builtin_amdgcn_sched_barrier(0);

    // compute tile tt from lds[buf]
#pragma unroll
    for (int n = 0; n < 4; ++n) {
      const int cread = w * 64 + n * 16 + col;
      float f[8];
#pragma unroll
      for (int j = 0; j < 8; ++j)
        f[j] = lds[buf][(g * 8 + j) * 260 + (cread ^ xr)];

      union { bf16x8 v; unsigned u[4]; } bh, bl;
#pragma unroll
      for (int j = 0; j < 4; ++j) {
        unsigned h = cvtpk(f[2 * j], f[2 * j + 1]);
        float h0f = __uint_as_float(h << 16);
        float h1f = __uint_as_float(h & 0xFFFF0000u);
        bh.u[j] = h;
        bl.u[j] = cvtpk(f[2 * j] - h0f, f[2 * j + 1] - h1f);
      }
#pragma unroll
      for (int m = 0; m < 4; ++m) acc[n][m] = __builtin_amdgcn_mfma_f32_16x16x32_bf16(ah[m], bh.v, acc[n][m], 0, 0, 0);
#pragma unroll
      for (int m = 0; m < 4; ++m) acc[n][m] = __builtin_amdgcn_mfma_f32_16x16x32_bf16(ah[m], bl.v, acc[n][m], 0, 0, 0);
#pragma unroll
      for (int m = 0; m < 4; ++m) acc[n][m] = __builtin_amdgcn_mfma_f32_16x16x32_bf16(al[m], bh.v, acc[n][m], 0, 0, 0);
    }
    __builtin_amdgcn_sched_barrier(0);

    // write next tile to the other buffer (b128, 16B-aligned, swizzled)
    if (tt + 1 < 16) {
#pragma unroll
      for (int i = 0; i < 8; ++i) {
        const int r = w + 4 * i;
        *(f32x4*)&lds[buf ^ 1][r * 260 + ((4 * l) ^ (((r >> 3) & 1) << 4))] = (f32x4)gg[i];
      }
    }
    __syncthreads();
  }

  float* pout = part2 + (size_t)blockIdx.y * ((size_t)64 * V_);
#pragma unroll
  for (int n = 0; n < 4; ++n) {
    const int c = c0 + w * 64 + n * 16 + col;
#pragma unroll
    for (int m = 0; m < 4; ++m)
#pragma unroll
      for (int i = 0; i < 4; ++i)
        pout[(size_t)(m * 16 + g * 4 + i) * V_ + c] = acc[n][m][i];
  }
}

// ---------------- softmax over rows (reads split-K partials + bias directly) -------------
#define SM_CHUNK 12565  // 4 * 12565 >= V_

__global__ void k_softmax1(const float* __restrict__ part2, const float* __restrict__ bs,
                           float2* __restrict__ stats) {
  __shared__ float smx[4], ssum[4];
  const int r = blockIdx.x >> 2, q = blockIdx.x & 3;
  const int beg = q * SM_CHUNK;
  const int end = (beg + SM_CHUNK < V_) ? beg + SM_CHUNK : V_;
  const float* p0 = part2 + (size_t)r * V_;
  const float* p1 = part2 + (size_t)64 * V_ + (size_t)r * V_;

  float mx = -3.4e38f;
  for (int i = beg + threadIdx.x; i < end; i += 256) mx = fmaxf(mx, p0[i] + p1[i] + bs[i]);
  mx = waveMax(mx);
  if ((threadIdx.x & 63) == 0) smx[threadIdx.x >> 6] = mx;
  __syncthreads();
  mx = fmaxf(fmaxf(smx[0], smx[1]), fmaxf(smx[2], smx[3]));

  float s = 0.f;
  for (int i = beg + threadIdx.x; i < end; i += 256) s += __expf(p0[i] + p1[i] + bs[i] - mx);
  s = waveSum(s);
  if ((threadIdx.x & 63) == 0) ssum[threadIdx.x >> 6] = s;
  __syncthreads();
  s = (ssum[0] + ssum[1]) + (ssum[2] + ssum[3]);

  if (threadIdx.x == 0) stats[blockIdx.x] = make_float2(mx, s);
}

__global__ void k_softmax2(const float* __restrict__ part2, const float* __restrict__ bs,
                           const float2* __restrict__ stats, float* __restrict__ out) {
  const int r = blockIdx.x >> 2, q = blockIdx.x & 3;
  float2 s0 = stats[r * 4 + 0], s1 = stats[r * 4 + 1];
  float2 s2 = stats[r * 4 + 2], s3 = stats[r * 4 + 3];
  float M = fmaxf(fmaxf(s0.x, s1.x), fmaxf(s2.x, s3.x));
  float S = s0.y * __expf(s0.x - M) + s1.y * __expf(s1.x - M)
          + s2.y * __expf(s2.x - M) + s3.y * __expf(s3.x - M);
  float inv = 1.f / S;
  const int beg = q * SM_CHUNK;
  const int end = (beg + SM_CHUNK < V_) ? beg + SM_CHUNK : V_;
  const float* p0 = part2 + (size_t)r * V_;
  const float* p1 = part2 + (size_t)64 * V_ + (size_t)r * V_;
  float* orow = out + (size_t)r * V_;
  for (int i = beg + threadIdx.x; i < end; i += 256)
    orow[i] = __expf(p0[i] + p1[i] + bs[i] - M) * inv;
}

// ---------------- launch ----------------
extern "C" void kernel_launch(void* const* d_in, const int* in_sizes, int n_in,
                              void* d_out, int out_size, void* d_ws, size_t ws_size,
                              hipStream_t stream) {
  const float* eh   = (const float*)d_in[0];
  const int*   ques = (const int*)d_in[1];
  const void*  mask = d_in[2];
  const float* emb  = (const float*)d_in[3];
  const float* W1   = (const float*)d_in[4];
  const float* b1   = (const float*)d_in[5];
  const float* W2   = (const float*)d_in[6];
  const float* b2   = (const float*)d_in[7];
  const float* A    = (const float*)d_in[8];
  const float* H    = (const float*)d_in[9];
  const float* Ws   = (const float*)d_in[10];
  const float* bs   = (const float*)d_in[11];
  float* out = (float*)d_out;
  char* ws = (char*)d_ws;

  float*          gpart   = (float*)(ws + 0);           // max 8,388,608
  float*          entpart = (float*)(ws + 12866048);    // 2,097,152
  float*          entsum  = (float*)(ws + 14963200);    // 4,096
  float*          hbuf    = (float*)(ws + 14967296);    // 524,288
  float*          qbuf    = (float*)(ws + 15491584);    // 262,144
  float*          ubuf    = (float*)(ws + 15753728);    // 262,144
  unsigned short* zpkh    = (unsigned short*)(ws + 16015872);  // 131,072
  unsigned short* zpkl    = (unsigned short*)(ws + 16146944);  // 131,072
  float2*         stats   = (float2*)(ws + 16278016);   // 2,048
  float*          part2   = (float*)(ws + 20971520);    // 25,731,584

  // P1: ent_partial (512 blocks) || h-gemm partials (512 blocks)
  k_p1<<<1024, 256, 0, stream>>>(eh, mask, entpart, ques, emb, W1, gpart);
  // P2: ent_reduce (4) || h = relu(.+b1) (512)
  k_p2<<<516, 256, 0, stream>>>(entpart, entsum, gpart, b1, hbuf);

  // P3/P4: q = h @ W2 + b2                 [64,1024], K=2048, split 32
  k_gemm64<<<dim3(16, 32), 256, 0, stream>>>(hbuf, W2, 2048, 1024, 64, gpart);
  k_reduce_t<32><<<256, 256, 0, stream>>>(gpart, 64 * 1024, 1024, b2, nullptr, 2, qbuf, nullptr, nullptr);

  // P5/P6: u = (q @ A) * ent_sum           [64,1024], split 16
  k_gemm64<<<dim3(16, 16), 256, 0, stream>>>(qbuf, A, 1024, 1024, 64, gpart);
  k_reduce_t<16><<<256, 256, 0, stream>>>(gpart, 64 * 1024, 1024, entsum, nullptr, 3, ubuf, nullptr, nullptr);

  // P7/P8: z = q + u @ H -> zpack bf16 hi/lo (MFMA-fragment order), split 16
  k_gemm64<<<dim3(16, 16), 256, 0, stream>>>(ubuf, H, 1024, 1024, 64, gpart);
  k_reduce_t<16><<<256, 256, 0, stream>>>(gpart, 64 * 1024, 1024, nullptr, qbuf, 4, nullptr, zpkh, zpkl);

  // P9: split-K partials = z @ Ws  [64,V]x2, 256-col tiles, 394 blocks
  k_gemm_big<<<dim3(197, 2), 256, 0, stream>>>(zpkh, zpkl, Ws, part2);

  // P10/P11: softmax two-pass over (p0+p1+bs)
  k_softmax1<<<256, 256, 0, stream>>>(part2, bs, stats);
  k_softmax2<<<256, 256, 0, stream>>>(part2, bs, stats, out);

  (void)in_sizes; (void)n_in; (void)out_size; (void)ws_size;
}

// Round 19
// 246.493 us; speedup vs baseline: 2.7626x; 1.0181x over previous
//
#include <hip/hip_runtime.h>
#include <stdint.h>

#define V_ 50257
#define D_ 1024
#define F_ 2048
#define B_ 64
#define E_ 512
#define ROWS_ (B_*E_)

typedef __attribute__((ext_vector_type(8))) short bf16x8;
typedef __attribute__((ext_vector_type(4))) float f32x4;
typedef __attribute__((ext_vector_type(4), aligned(4))) float f32x4a;  // 4B-aligned global loads
typedef __attribute__((ext_vector_type(4))) unsigned u32x4;

__device__ __forceinline__ unsigned rne1(float a) {
  unsigned u = __float_as_uint(a);
  return (u + 0x7FFFu + ((u >> 16) & 1u)) >> 16;
}

// packed bf16 convert: r = bf16(a) | bf16(b)<<16, 1 VALU op per pair.
// hi rounding mode irrelevant for the split (lo = rne(s - ACTUAL hif) self-corrects).
__device__ __forceinline__ unsigned cvtpk(float a, float b) {
  unsigned r;
  asm("v_cvt_pk_bf16_f32 %0, %1, %2" : "=v"(r) : "v"(a), "v"(b));
  return r;
}

__device__ __forceinline__ float waveMax(float v) {
#pragma unroll
  for (int o = 32; o > 0; o >>= 1) v = fmaxf(v, __shfl_xor(v, o, 64));
  return v;
}
__device__ __forceinline__ float waveSum(float v) {
#pragma unroll
  for (int o = 32; o > 0; o >>= 1) v += __shfl_xor(v, o, 64);
  return v;
}

// ---------------- device bodies ----------------

// ent partials: branch-free (multiply by mask), 4-row unroll for load pipelining.
__device__ __forceinline__ void ent_partial_body(int bid, const float* __restrict__ eh,
                                                 const void* __restrict__ mask,
                                                 float* __restrict__ part) {
  __shared__ int s_mode;
  const int tid = threadIdx.x;
  const uint32_t* mu = (const uint32_t*)mask;
  int f = 0;
  for (int i = tid; i < (ROWS_ / 4); i += 256) {
    uint32_t u = mu[i];
    if (u == 0x3F800000u) f |= 2;
    else if (u & 0xFFFFFF00u) f |= 1;
  }
  if (tid == 0) s_mode = 0;
  __syncthreads();
  if (f) atomicOr(&s_mode, f);
  __syncthreads();
  const int sm = s_mode;
  const int mode = (sm & 1) ? 1 : ((sm & 2) ? 2 : 0);

  float4 acc = make_float4(0.f, 0.f, 0.f, 0.f);
  const float4* eh4 = (const float4*)eh;
#pragma unroll 1
  for (int i = 0; i < 64; i += 4) {
    int r[4];
    float m[4];
    float4 v[4];
#pragma unroll
    for (int u = 0; u < 4; ++u) r[u] = bid + (i + u) * 512;
#pragma unroll
    for (int u = 0; u < 4; ++u) {
      if (mode == 1)      m[u] = ((const unsigned char*)mask)[r[u]] ? 1.f : 0.f;
      else if (mode == 2) m[u] = ((const float*)mask)[r[u]] != 0.f ? 1.f : 0.f;
      else                m[u] = ((const int*)mask)[r[u]] ? 1.f : 0.f;
    }
#pragma unroll
    for (int u = 0; u < 4; ++u) v[u] = eh4[(size_t)r[u] * (D_ / 4) + tid];
#pragma unroll
    for (int u = 0; u < 4; ++u) {
      acc.x = fmaf(m[u], v[u].x, acc.x);
      acc.y = fmaf(m[u], v[u].y, acc.y);
      acc.z = fmaf(m[u], v[u].z, acc.z);
      acc.w = fmaf(m[u], v[u].w, acc.w);
    }
  }
  ((float4*)part)[(size_t)bid * (D_ / 4) + tid] = acc;
}

__device__ __forceinline__ void ent_reduce_body(int bid, const float* __restrict__ part,
                                                float* __restrict__ entsum) {
  int d = bid * 256 + threadIdx.x;
  float s0 = 0.f, s1 = 0.f, s2 = 0.f, s3 = 0.f;
#pragma unroll 8
  for (int i = 0; i < 512; i += 4) {
    s0 += part[(size_t)(i    ) * D_ + d];
    s1 += part[(size_t)(i + 1) * D_ + d];
    s2 += part[(size_t)(i + 2) * D_ + d];
    s3 += part[(size_t)(i + 3) * D_ + d];
  }
  entsum[d] = (s0 + s1) + (s2 + s3);
}

__device__ __forceinline__ void gemm64_body(int bx, int by, const float* __restrict__ X,
                                            const int* __restrict__ gatherIdx,
                                            const float* __restrict__ emb,
                                            const float* __restrict__ W,
                                            int K, int N, int KB, float* __restrict__ part) {
  const int l  = threadIdx.x & 63;
  const int rg = __builtin_amdgcn_readfirstlane((int)(threadIdx.x >> 6));
  const int c  = bx * 64 + l;
  const int k0 = by * KB;
  const int m0 = rg * 16;

  const float* Xp = gatherIdx ? emb : X;
  int rb[16];
#pragma unroll
  for (int r = 0; r < 16; ++r) {
    int m = m0 + r;
    rb[r] = gatherIdx ? gatherIdx[m] * K : m * K;
  }

  float acc[16];
#pragma unroll
  for (int r = 0; r < 16; ++r) acc[r] = 0.f;

  for (int k = k0; k < k0 + KB; k += 8) {
    float wv[8];
#pragma unroll
    for (int j = 0; j < 8; ++j) wv[j] = W[(size_t)(k + j) * N + c];
#pragma unroll
    for (int r = 0; r < 16; ++r) {
      float4 x0 = *(const float4*)&Xp[rb[r] + k];
      float4 x1 = *(const float4*)&Xp[rb[r] + k + 4];
      acc[r] = fmaf(x0.x, wv[0], acc[r]);
      acc[r] = fmaf(x0.y, wv[1], acc[r]);
      acc[r] = fmaf(x0.z, wv[2], acc[r]);
      acc[r] = fmaf(x0.w, wv[3], acc[r]);
      acc[r] = fmaf(x1.x, wv[4], acc[r]);
      acc[r] = fmaf(x1.y, wv[5], acc[r]);
      acc[r] = fmaf(x1.z, wv[6], acc[r]);
      acc[r] = fmaf(x1.w, wv[7], acc[r]);
    }
  }
  size_t base = (size_t)by * ((size_t)64 * N);
#pragma unroll
  for (int r = 0; r < 16; ++r) part[base + (size_t)(m0 + r) * N + c] = acc[r];
}

// reduce split-K partials + epilogue, compile-time NSPLIT.
// mode 1: relu(x+vecB[c]); 2: x+vecB[c]; 3: x*vecB[c];
// mode 4: idx is zpack DEST index; gathers src, writes bf16 hi/lo in MFMA-fragment order.
template<int NSPLIT>
__device__ __forceinline__ void reduce_body_t(int bid, const float* __restrict__ part,
                                              int MN, int N,
                                              const float* __restrict__ vecB,
                                              const float* __restrict__ addend,
                                              int mode, float* __restrict__ dst,
                                              unsigned short* __restrict__ ph,
                                              unsigned short* __restrict__ pl) {
  int idx = bid * 256 + threadIdx.x;
  if (idx >= MN) return;

  if (mode == 4) {
    const int d   = idx;
    const int j   = d & 7;
    const int l   = (d >> 3) & 63;
    const int m   = (d >> 9) & 3;
    const int tg  = d >> 11;
    const int col = l & 15;
    const int g   = l >> 4;
    const int row = m * 16 + col;
    const int kk  = tg * 32 + g * 8 + j;
    const int src = row * 1024 + kk;
    float s = 0.f;
#pragma unroll
    for (int i = 0; i < NSPLIT; ++i) s += part[(size_t)i * MN + src];
    s += addend[src];
    unsigned hi = rne1(s);
    float hif = __uint_as_float(hi << 16);
    ph[d] = (unsigned short)hi;
    pl[d] = (unsigned short)rne1(s - hif);
    return;
  }

  float s = 0.f;
#pragma unroll
  for (int i = 0; i < NSPLIT; ++i) s += part[(size_t)i * MN + idx];
  int c = idx & (N - 1);
  if (mode == 1)      { s += vecB[c]; s = s > 0.f ? s : 0.f; dst[idx] = s; }
  else if (mode == 2) { s += vecB[c]; dst[idx] = s; }
  else                { s *= vecB[c]; dst[idx] = s; }
}

// ---------------- phase kernels ----------------
__global__ void k_p1(const float* __restrict__ eh, const void* __restrict__ mask,
                     float* __restrict__ entpart, const int* __restrict__ ques,
                     const float* __restrict__ emb, const float* __restrict__ W1,
                     float* __restrict__ gpart) {
  int bid = blockIdx.x;
  if (bid < 512) ent_partial_body(bid, eh, mask, entpart);
  else {
    int b2 = bid - 512;
    gemm64_body(b2 & 31, b2 >> 5, nullptr, ques, emb, W1, 1024, 2048, 64, gpart);
  }
}

__global__ void k_p2(const float* __restrict__ entpart, float* __restrict__ entsum,
                     const float* __restrict__ gpart, const float* __restrict__ b1,
                     float* __restrict__ hbuf) {
  int bid = blockIdx.x;
  if (bid < 4) ent_reduce_body(bid, entpart, entsum);
  else reduce_body_t<16>(bid - 4, gpart, 64 * 2048, 2048, b1, nullptr, 1, hbuf, nullptr, nullptr);
}

__global__ void k_gemm64(const float* __restrict__ X, const float* __restrict__ W,
                         int K, int N, int KB, float* __restrict__ part) {
  gemm64_body(blockIdx.x, blockIdx.y, X, nullptr, nullptr, W, K, N, KB, part);
}

template<int NSPLIT>
__global__ void k_reduce_t(const float* __restrict__ part, int MN, int N,
                           const float* __restrict__ vecB, const float* __restrict__ addend,
                           int mode, float* __restrict__ dst,
                           unsigned short* __restrict__ ph, unsigned short* __restrict__ pl) {
  reduce_body_t<NSPLIT>(blockIdx.x, part, MN, N, vecB, addend, mode, dst, ph, pl);
}

// ---------------- big GEMM: split-K partials, 256-col tiles, split-bf16 MFMA -------------
// Round-19 redesign for VMEM instruction economy (z was loaded redundantly by all 4 waves:
// 32 KB/block-iter where only 8 KB is unique -> half of all VMEM issue slots):
//  - z staged once per block into PLANAR LDS (2 dwordx4 loads/thread, -75% z VMEM instrs);
//    frags rebuilt via ds_read_b32 at [j][m][lane] (bank l%32: 2-way, free).
//  - Ws single-buffered [32][256] f32 (stride 256, XOR swizzle key (g&1)<<4 as in r16/18;
//    no pad needed: the swizzle splits g-parity across 16-bank halves).
//  - LDS total 40,960 B -> 3 blocks/CU (launch_bounds(256,3)), 12 waves/CU; cross-block
//    interleave covers the 2-sync iteration: loads(t+1) -> sched_barrier -> compute(t)
//    -> syncA -> LDS writes(t+1) -> syncB.
__global__ __launch_bounds__(256, 3) void k_gemm_big(const unsigned short* __restrict__ zpkh,
                                                     const unsigned short* __restrict__ zpkl,
                                                     const float* __restrict__ Ws,
                                                     float* __restrict__ part2) {
  __shared__ float wslds[32 * 256];    // 32,768 B
  __shared__ unsigned zlds[2048];      // 8,192 B: hi plane [j][m][l] at j*256+m*64+l, lo at +1024
  const int t   = threadIdx.x;
  const int l   = t & 63;
  const int w   = t >> 6;              // wave 0..3
  const int col = l & 15;
  const int g   = l >> 4;              // k-chunk g*8..g*8+7
  const int zm  = w;                   // this thread stages z-frag (m = w, lane = l)
  const int c0  = (blockIdx.x < 196) ? blockIdx.x * 256 : (V_ - 256);
  const int kbase = blockIdx.y * 512;
  const int xr  = (g & 1) << 4;        // read-side XOR key

  f32x4 acc[4][4];  // [n][m]
#pragma unroll
  for (int n = 0; n < 4; ++n)
#pragma unroll
    for (int m = 0; m < 4; ++m) acc[n][m] = (f32x4){0.f, 0.f, 0.f, 0.f};

  // prologue: stage tile 0 (Ws rows kbase..kbase+31; z tile-group kbase/32)
  {
    f32x4a gg[8];
#pragma unroll
    for (int i = 0; i < 8; ++i)
      gg[i] = *(const f32x4a*)(Ws + (size_t)(kbase + w + 4 * i) * V_ + c0 + 4 * l);
    const int tg0 = kbase >> 5;
    const int zb  = ((tg0 * 4 + zm) * 64 + l) * 8;
    u32x4 zh4 = *(const u32x4*)(zpkh + zb);
    u32x4 zl4 = *(const u32x4*)(zpkl + zb);
#pragma unroll
    for (int i = 0; i < 8; ++i) {
      const int r = w + 4 * i;
      *(f32x4*)&wslds[r * 256 + ((4 * l) ^ (((r >> 3) & 1) << 4))] = (f32x4)gg[i];
    }
#pragma unroll
    for (int j = 0; j < 4; ++j) {
      zlds[j * 256 + zm * 64 + l]        = zh4[j];
      zlds[1024 + j * 256 + zm * 64 + l] = zl4[j];
    }
  }
  __syncthreads();

  for (int tt = 0; tt < 16; ++tt) {
    // issue next-tile loads first (latency hides under compute(t))
    f32x4a gg[8];
    u32x4 zh4, zl4;
    if (tt + 1 < 16) {
      const float* wb = Ws + (size_t)(kbase + (tt + 1) * 32) * V_ + c0 + 4 * l;
#pragma unroll
      for (int i = 0; i < 8; ++i)
        gg[i] = *(const f32x4a*)(wb + (size_t)(w + 4 * i) * V_);
      const int tgn = (kbase >> 5) + tt + 1;
      const int zb  = ((tgn * 4 + zm) * 64 + l) * 8;
      zh4 = *(const u32x4*)(zpkh + zb);
      zl4 = *(const u32x4*)(zpkl + zb);
    }
    __builtin_amdgcn_sched_barrier(0);

    // z-frags from planar LDS (each thread reads its own lane's fragments)
    union { bf16x8 v; unsigned u[4]; } ah[4], al[4];
#pragma unroll
    for (int m = 0; m < 4; ++m)
#pragma unroll
      for (int j = 0; j < 4; ++j) {
        ah[m].u[j] = zlds[j * 256 + m * 64 + l];
        al[m].u[j] = zlds[1024 + j * 256 + m * 64 + l];
      }

    // compute tile tt from wslds
#pragma unroll
    for (int n = 0; n < 4; ++n) {
      const int cread = w * 64 + n * 16 + col;
      float f[8];
#pragma unroll
      for (int j = 0; j < 8; ++j)
        f[j] = wslds[(g * 8 + j) * 256 + (cread ^ xr)];

      union { bf16x8 v; unsigned u[4]; } bh, bl;
#pragma unroll
      for (int j = 0; j < 4; ++j) {
        unsigned h = cvtpk(f[2 * j], f[2 * j + 1]);
        float h0f = __uint_as_float(h << 16);
        float h1f = __uint_as_float(h & 0xFFFF0000u);
        bh.u[j] = h;
        bl.u[j] = cvtpk(f[2 * j] - h0f, f[2 * j + 1] - h1f);
      }
#pragma unroll
      for (int m = 0; m < 4; ++m) acc[n][m] = __builtin_amdgcn_mfma_f32_16x16x32_bf16(ah[m].v, bh.v, acc[n][m], 0, 0, 0);
#pragma unroll
      for (int m = 0; m < 4; ++m) acc[n][m] = __builtin_amdgcn_mfma_f32_16x16x32_bf16(ah[m].v, bl.v, acc[n][m], 0, 0, 0);
#pragma unroll
      for (int m = 0; m < 4; ++m) acc[n][m] = __builtin_amdgcn_mfma_f32_16x16x32_bf16(al[m].v, bh.v, acc[n][m], 0, 0, 0);
    }

    __syncthreads();  // A: all reads of wslds/zlds done

    if (tt + 1 < 16) {
#pragma unroll
      for (int i = 0; i < 8; ++i) {
        const int r = w + 4 * i;
        *(f32x4*)&wslds[r * 256 + ((4 * l) ^ (((r >> 3) & 1) << 4))] = (f32x4)gg[i];
      }
#pragma unroll
      for (int j = 0; j < 4; ++j) {
        zlds[j * 256 + zm * 64 + l]        = zh4[j];
        zlds[1024 + j * 256 + zm * 64 + l] = zl4[j];
      }
    }
    __syncthreads();  // B: next tile visible
  }

  float* pout = part2 + (size_t)blockIdx.y * ((size_t)64 * V_);
#pragma unroll
  for (int n = 0; n < 4; ++n) {
    const int c = c0 + w * 64 + n * 16 + col;
#pragma unroll
    for (int m = 0; m < 4; ++m)
#pragma unroll
      for (int i = 0; i < 4; ++i)
        pout[(size_t)(m * 16 + g * 4 + i) * V_ + c] = acc[n][m][i];
  }
}

// ---------------- softmax over rows (reads split-K partials + bias directly) -------------
#define SM_CHUNK 12565  // 4 * 12565 >= V_

__global__ void k_softmax1(const float* __restrict__ part2, const float* __restrict__ bs,
                           float2* __restrict__ stats) {
  __shared__ float smx[4], ssum[4];
  const int r = blockIdx.x >> 2, q = blockIdx.x & 3;
  const int beg = q * SM_CHUNK;
  const int end = (beg + SM_CHUNK < V_) ? beg + SM_CHUNK : V_;
  const float* p0 = part2 + (size_t)r * V_;
  const float* p1 = part2 + (size_t)64 * V_ + (size_t)r * V_;

  float mx = -3.4e38f;
  for (int i = beg + threadIdx.x; i < end; i += 256) mx = fmaxf(mx, p0[i] + p1[i] + bs[i]);
  mx = waveMax(mx);
  if ((threadIdx.x & 63) == 0) smx[threadIdx.x >> 6] = mx;
  __syncthreads();
  mx = fmaxf(fmaxf(smx[0], smx[1]), fmaxf(smx[2], smx[3]));

  float s = 0.f;
  for (int i = beg + threadIdx.x; i < end; i += 256) s += __expf(p0[i] + p1[i] + bs[i] - mx);
  s = waveSum(s);
  if ((threadIdx.x & 63) == 0) ssum[threadIdx.x >> 6] = s;
  __syncthreads();
  s = (ssum[0] + ssum[1]) + (ssum[2] + ssum[3]);

  if (threadIdx.x == 0) stats[blockIdx.x] = make_float2(mx, s);
}

__global__ void k_softmax2(const float* __restrict__ part2, const float* __restrict__ bs,
                           const float2* __restrict__ stats, float* __restrict__ out) {
  const int r = blockIdx.x >> 2, q = blockIdx.x & 3;
  float2 s0 = stats[r * 4 + 0], s1 = stats[r * 4 + 1];
  float2 s2 = stats[r * 4 + 2], s3 = stats[r * 4 + 3];
  float M = fmaxf(fmaxf(s0.x, s1.x), fmaxf(s2.x, s3.x));
  float S = s0.y * __expf(s0.x - M) + s1.y * __expf(s1.x - M)
          + s2.y * __expf(s2.x - M) + s3.y * __expf(s3.x - M);
  float inv = 1.f / S;
  const int beg = q * SM_CHUNK;
  const int end = (beg + SM_CHUNK < V_) ? beg + SM_CHUNK : V_;
  const float* p0 = part2 + (size_t)r * V_;
  const float* p1 = part2 + (size_t)64 * V_ + (size_t)r * V_;
  float* orow = out + (size_t)r * V_;
  for (int i = beg + threadIdx.x; i < end; i += 256)
    orow[i] = __expf(p0[i] + p1[i] + bs[i] - M) * inv;
}

// ---------------- launch ----------------
extern "C" void kernel_launch(void* const* d_in, const int* in_sizes, int n_in,
                              void* d_out, int out_size, void* d_ws, size_t ws_size,
                              hipStream_t stream) {
  const float* eh   = (const float*)d_in[0];
  const int*   ques = (const int*)d_in[1];
  const void*  mask = d_in[2];
  const float* emb  = (const float*)d_in[3];
  const float* W1   = (const float*)d_in[4];
  const float* b1   = (const float*)d_in[5];
  const float* W2   = (const float*)d_in[6];
  const float* b2   = (const float*)d_in[7];
  const float* A    = (const float*)d_in[8];
  const float* H    = (const float*)d_in[9];
  const float* Ws   = (const float*)d_in[10];
  const float* bs   = (const float*)d_in[11];
  float* out = (float*)d_out;
  char* ws = (char*)d_ws;

  float*          gpart   = (float*)(ws + 0);           // max 8,388,608
  float*          entpart = (float*)(ws + 12866048);    // 2,097,152
  float*          entsum  = (float*)(ws + 14963200);    // 4,096
  float*          hbuf    = (float*)(ws + 14967296);    // 524,288
  float*          qbuf    = (float*)(ws + 15491584);    // 262,144
  float*          ubuf    = (float*)(ws + 15753728);    // 262,144
  unsigned short* zpkh    = (unsigned short*)(ws + 16015872);  // 131,072
  unsigned short* zpkl    = (unsigned short*)(ws + 16146944);  // 131,072
  float2*         stats   = (float2*)(ws + 16278016);   // 2,048
  float*          part2   = (float*)(ws + 20971520);    // 25,731,584

  // P1: ent_partial (512 blocks) || h-gemm partials (512 blocks)
  k_p1<<<1024, 256, 0, stream>>>(eh, mask, entpart, ques, emb, W1, gpart);
  // P2: ent_reduce (4) || h = relu(.+b1) (512)
  k_p2<<<516, 256, 0, stream>>>(entpart, entsum, gpart, b1, hbuf);

  // P3/P4: q = h @ W2 + b2                 [64,1024], K=2048, split 32
  k_gemm64<<<dim3(16, 32), 256, 0, stream>>>(hbuf, W2, 2048, 1024, 64, gpart);
  k_reduce_t<32><<<256, 256, 0, stream>>>(gpart, 64 * 1024, 1024, b2, nullptr, 2, qbuf, nullptr, nullptr);

  // P5/P6: u = (q @ A) * ent_sum           [64,1024], split 16
  k_gemm64<<<dim3(16, 16), 256, 0, stream>>>(qbuf, A, 1024, 1024, 64, gpart);
  k_reduce_t<16><<<256, 256, 0, stream>>>(gpart, 64 * 1024, 1024, entsum, nullptr, 3, ubuf, nullptr, nullptr);

  // P7/P8: z = q + u @ H -> zpack bf16 hi/lo (MFMA-fragment order), split 16
  k_gemm64<<<dim3(16, 16), 256, 0, stream>>>(ubuf, H, 1024, 1024, 64, gpart);
  k_reduce_t<16><<<256, 256, 0, stream>>>(gpart, 64 * 1024, 1024, nullptr, qbuf, 4, nullptr, zpkh, zpkl);

  // P9: split-K partials = z @ Ws  [64,V]x2, 256-col tiles, 394 blocks, z-via-LDS
  k_gemm_big<<<dim3(197, 2), 256, 0, stream>>>(zpkh, zpkl, Ws, part2);

  // P10/P11: softmax two-pass over (p0+p1+bs)
  k_softmax1<<<256, 256, 0, stream>>>(part2, bs, stats);
  k_softmax2<<<256, 256, 0, stream>>>(part2, bs, stats, out);

  (void)in_sizes; (void)n_in; (void)out_size; (void)ws_size;
}